// Round 5
// baseline (150.876 us; speedup 1.0000x reference)
//
#include <hip/hip_runtime.h>
#include <math.h>

// SineGenVITS: B=16, L=131072, DIM=9. out = [sine (B,L,9) | uv (B,L,1) | noise (B,L,9)] f32.
//
// phase[b,t,d] = frac( k_d * C_t / SR + rand_ini[b,d] ),  C_t = sum f0[b,0..t] (f64 exact).
// The reference's integer wrap-shifts vanish mod 1; its own f32 error >> ours.
//
// Single fused kernel. Cross-chunk prefix via decoupled lookback in d_ws:
// each block publishes its chunk's f64 sum (release store + flag), then
// acquire-polls its <=63 predecessors and tree-reduces in fixed lane order
// (deterministic: aggregates are exact call-invariant doubles). Flags are
// cleared by a 4KB hipMemsetAsync at the head of every call (no cross-call
// state). All 1024 blocks co-resident: LDS 18.5KB, __launch_bounds__(256,4).

#define Bq 16
#define Lq 131072
#define DIMq 9
#define CHUNK 2048
#define NCHUNK (Lq / CHUNK)  // 64
#define NBLK (Bq * NCHUNK)   // 1024
#define NT 256
#define PT 8                         // timesteps per thread
#define Q4 (CHUNK * DIMq / 4 / NT)   // 18 float4s per thread in phase 2

typedef float f32x4 __attribute__((ext_vector_type(4)));

__global__ void __launch_bounds__(NT, 4) k_fused(
    const float* __restrict__ f0, const float* __restrict__ rini,
    const float* __restrict__ nz, double* __restrict__ agg,
    unsigned* __restrict__ flags, float* __restrict__ out0,
    float* __restrict__ out1, float* __restrict__ out2) {
  int bc = blockIdx.x;
  int b = bc >> 6, c = bc & 63;
  int tid = threadIdx.x, lane = tid & 63, wave = tid >> 6;
  size_t t0g = (size_t)b * Lq + (size_t)c * CHUNK;

  __shared__ float p1s[CHUNK + CHUNK / 8];   // frac(C_t/SR), pad-8: idx t+(t>>3)
  __shared__ float nmps[CHUNK + CHUNK / 8];  // +0.003 voiced / -(0.1/3) unvoiced
  __shared__ float inis[DIMq];
  __shared__ double wsum[NT / 64];

  // ---- load f0 chunk (single read), thread-local + wave f64 scan ----
  const f32x4* fp = (const f32x4*)(f0 + t0g + tid * PT);
  f32x4 fa = fp[0];
  f32x4 fb = fp[1];
  float fv[PT] = {fa.x, fa.y, fa.z, fa.w, fb.x, fb.y, fb.z, fb.w};
  double run = 0.0, inc[PT];
#pragma unroll
  for (int j = 0; j < PT; ++j) { run += (double)fv[j]; inc[j] = run; }
  double tot = run;
#pragma unroll
  for (int d = 1; d < 64; d <<= 1) {
    double o = __shfl_up(tot, d, 64);
    if (lane >= d) tot += o;
  }
  if (lane == 63) wsum[wave] = tot;
  if (tid < DIMq) inis[tid] = rini[b * DIMq + tid];
  __syncthreads();

  // ---- publish this chunk's aggregate ----
  if (tid == 0) {
    double a = (wsum[0] + wsum[1]) + (wsum[2] + wsum[3]);
    agg[bc] = a;
    __hip_atomic_store(&flags[bc], 1u, __ATOMIC_RELEASE, __HIP_MEMORY_SCOPE_AGENT);
  }

  // ---- lookback: sum predecessors' aggregates (redundant per wave) ----
  double pv = 0.0;
  if (lane < c) {
    const unsigned* fl = flags + (b << 6) + lane;
    while (__hip_atomic_load(fl, __ATOMIC_ACQUIRE, __HIP_MEMORY_SCOPE_AGENT) != 1u)
      __builtin_amdgcn_s_sleep(1);
    pv = __hip_atomic_load(&agg[(b << 6) + lane], __ATOMIC_RELAXED,
                           __HIP_MEMORY_SCOPE_AGENT);
  }
#pragma unroll
  for (int d = 32; d > 0; d >>= 1) pv += __shfl_xor(pv, d, 64);
  double wpre = 0.0;
  for (int w = 0; w < wave; ++w) wpre += wsum[w];
  double base = pv + wpre + (tot - run);  // exclusive prefix for this thread

  const double invsr = 1.0 / 22050.0;
  const float nampU = (float)(0.1 / 3.0);
  float uvv[PT];
#pragma unroll
  for (int j = 0; j < PT; ++j) {
    double ph = (base + inc[j]) * invsr;
    ph -= floor(ph);
    int t = tid * PT + j;
    p1s[t + (t >> 3)] = (float)ph;
    bool v = fv[j] > 0.0f;
    nmps[t + (t >> 3)] = v ? 0.003f : -nampU;
    uvv[j] = v ? 1.0f : 0.0f;
  }
  f32x4 u0 = {uvv[0], uvv[1], uvv[2], uvv[3]};
  f32x4 u1 = {uvv[4], uvv[5], uvv[6], uvv[7]};
  __builtin_nontemporal_store(u0, (f32x4*)(out1 + t0g + tid * PT));
  __builtin_nontemporal_store(u1, (f32x4*)(out1 + t0g + tid * PT + 4));
  __syncthreads();

  // ---- phase 2: flat float4 elementwise over chunk*9 elements ----
  const f32x4* nzc = (const f32x4*)(nz + t0g * DIMq);
  f32x4* o0c = (f32x4*)(out0 + t0g * DIMq);
  f32x4* o2c = (f32x4*)(out2 + t0g * DIMq);

  struct R { float r0, r2; };
  auto gen = [&](int t, int d, float nzv) -> R {
    int ti = t + (t >> 3);
    float p1 = p1s[ti], nm = nmps[ti];
    float ph = (float)(d + 1) * p1 + inis[d];
    ph -= floorf(ph);
    float s = __builtin_amdgcn_sinf(ph) * 0.1f;
    float noise = fabsf(nm) * nzv;
    R r;
    r.r2 = noise;
    r.r0 = (nm > 0.0f) ? s + noise : noise;
    return r;
  };

#pragma unroll 6
  for (int w = 0; w < Q4; ++w) {
    int q = w * NT + tid;
    int e = q * 4;
    int t = (int)(((unsigned)e * 7282u) >> 16);  // e/9, exact for e<18432
    int d = e - t * 9;
    f32x4 nzv = __builtin_nontemporal_load(&nzc[q]);
    R a = gen(t, d, nzv.x); if (++d == 9) { d = 0; ++t; }
    R bb = gen(t, d, nzv.y); if (++d == 9) { d = 0; ++t; }
    R cc = gen(t, d, nzv.z); if (++d == 9) { d = 0; ++t; }
    R dd = gen(t, d, nzv.w);
    f32x4 r0 = {a.r0, bb.r0, cc.r0, dd.r0};
    f32x4 r2 = {a.r2, bb.r2, cc.r2, dd.r2};
    __builtin_nontemporal_store(r0, &o0c[q]);
    __builtin_nontemporal_store(r2, &o2c[q]);
  }
}

extern "C" void kernel_launch(void* const* d_in, const int* in_sizes, int n_in,
                              void* d_out, int out_size, void* d_ws, size_t ws_size,
                              hipStream_t stream) {
  const float* f0 = (const float*)d_in[0];
  const float* rini = (const float*)d_in[1];
  const float* nz = (const float*)d_in[2];
  float* out = (float*)d_out;
  float* out0 = out;                           // sine_waves (B,L,9)
  float* out1 = out + (size_t)Bq * Lq * DIMq;  // uv (B,L,1)
  float* out2 = out1 + (size_t)Bq * Lq;        // noise (B,L,9)
  double* agg = (double*)d_ws;                 // NBLK doubles = 8 KB
  unsigned* flags = (unsigned*)((char*)d_ws + NBLK * sizeof(double));  // 4 KB

  (void)hipMemsetAsync(flags, 0, NBLK * sizeof(unsigned), stream);
  k_fused<<<NBLK, NT, 0, stream>>>(f0, rini, nz, agg, flags, out0, out1, out2);
}

// Round 6
// 58.114 us; speedup vs baseline: 2.5962x; 2.5962x over previous
//
#include <hip/hip_runtime.h>
#include <math.h>

// SineGenVITS: B=16, L=131072, DIM=9. out = [sine (B,L,9) | uv (B,L,1) | noise (B,L,9)] f32.
//
// phase[b,t,d] = frac( k_d * C_t / SR + rand_ini[b,d] ),  C_t = sum f0[b,0..t] (f64 exact).
// The reference's integer wrap-shifts vanish mod 1; its own f32 error >> ours.
//
// Single fused kernel; cross-chunk prefix via decoupled lookback in d_ws.
// COHERENCE NOTE (gfx950): agent-scope acquire/release emit whole-L2
// invalidate/writeback (per-XCD L2s non-coherent) -> a spin loop with acquire
// was a chip-wide cache storm (R5: 153us, 1.3TB/s). Use RELAXED atomics only
// (plain sc0/sc1 loads/stores to the L3 coherence point, no cache ops);
// publisher orders agg-before-flag with an explicit s_waitcnt vmcnt(0).
// Flags cleared by a 4KB hipMemsetAsync each call (no cross-call state).

#define Bq 16
#define Lq 131072
#define DIMq 9
#define CHUNK 2048
#define NCHUNK (Lq / CHUNK)  // 64
#define NBLK (Bq * NCHUNK)   // 1024
#define NT 256
#define PT 8                         // timesteps per thread
#define Q4 (CHUNK * DIMq / 4 / NT)   // 18 float4s per thread in phase 2

typedef float f32x4 __attribute__((ext_vector_type(4)));

__global__ void __launch_bounds__(NT, 4) k_fused(
    const float* __restrict__ f0, const float* __restrict__ rini,
    const float* __restrict__ nz, double* __restrict__ agg,
    unsigned* __restrict__ flags, float* __restrict__ out0,
    float* __restrict__ out1, float* __restrict__ out2) {
  int bc = blockIdx.x;
  int b = bc >> 6, c = bc & 63;
  int tid = threadIdx.x, lane = tid & 63, wave = tid >> 6;
  size_t t0g = (size_t)b * Lq + (size_t)c * CHUNK;

  __shared__ float p1s[CHUNK + CHUNK / 8];   // frac(C_t/SR), pad-8: idx t+(t>>3)
  __shared__ float nmps[CHUNK + CHUNK / 8];  // +0.003 voiced / -(0.1/3) unvoiced
  __shared__ float inis[DIMq];
  __shared__ double wsum[NT / 64];

  // ---- load f0 chunk (single read), thread-local + wave f64 scan ----
  const f32x4* fp = (const f32x4*)(f0 + t0g + tid * PT);
  f32x4 fa = fp[0];
  f32x4 fb = fp[1];
  float fv[PT] = {fa.x, fa.y, fa.z, fa.w, fb.x, fb.y, fb.z, fb.w};
  double run = 0.0, inc[PT];
#pragma unroll
  for (int j = 0; j < PT; ++j) { run += (double)fv[j]; inc[j] = run; }
  double tot = run;
#pragma unroll
  for (int d = 1; d < 64; d <<= 1) {
    double o = __shfl_up(tot, d, 64);
    if (lane >= d) tot += o;
  }
  if (lane == 63) wsum[wave] = tot;
  if (tid < DIMq) inis[tid] = rini[b * DIMq + tid];
  __syncthreads();

  // ---- publish this chunk's aggregate (relaxed + vmcnt ordering) ----
  if (tid == 0) {
    double a = (wsum[0] + wsum[1]) + (wsum[2] + wsum[3]);
    __hip_atomic_store(&agg[bc], a, __ATOMIC_RELAXED, __HIP_MEMORY_SCOPE_AGENT);
    asm volatile("s_waitcnt vmcnt(0)" ::: "memory");
    __hip_atomic_store(&flags[bc], 1u, __ATOMIC_RELAXED, __HIP_MEMORY_SCOPE_AGENT);
  }

  // ---- lookback: relaxed poll, then relaxed read (redundant per wave) ----
  double pv = 0.0;
  if (lane < c) {
    const unsigned* fl = flags + (b << 6) + lane;
    while (__hip_atomic_load(fl, __ATOMIC_RELAXED, __HIP_MEMORY_SCOPE_AGENT) != 1u)
      __builtin_amdgcn_s_sleep(2);
    pv = __hip_atomic_load(&agg[(b << 6) + lane], __ATOMIC_RELAXED,
                           __HIP_MEMORY_SCOPE_AGENT);
  }
#pragma unroll
  for (int d = 32; d > 0; d >>= 1) pv += __shfl_xor(pv, d, 64);
  double wpre = 0.0;
  for (int w = 0; w < wave; ++w) wpre += wsum[w];
  double base = pv + wpre + (tot - run);  // exclusive prefix for this thread

  const double invsr = 1.0 / 22050.0;
  const float nampU = (float)(0.1 / 3.0);
  float uvv[PT];
#pragma unroll
  for (int j = 0; j < PT; ++j) {
    double ph = (base + inc[j]) * invsr;
    ph -= floor(ph);
    int t = tid * PT + j;
    p1s[t + (t >> 3)] = (float)ph;
    bool v = fv[j] > 0.0f;
    nmps[t + (t >> 3)] = v ? 0.003f : -nampU;
    uvv[j] = v ? 1.0f : 0.0f;
  }
  f32x4 u0 = {uvv[0], uvv[1], uvv[2], uvv[3]};
  f32x4 u1 = {uvv[4], uvv[5], uvv[6], uvv[7]};
  __builtin_nontemporal_store(u0, (f32x4*)(out1 + t0g + tid * PT));
  __builtin_nontemporal_store(u1, (f32x4*)(out1 + t0g + tid * PT + 4));
  __syncthreads();

  // ---- phase 2: flat float4 elementwise over chunk*9 elements ----
  const f32x4* nzc = (const f32x4*)(nz + t0g * DIMq);
  f32x4* o0c = (f32x4*)(out0 + t0g * DIMq);
  f32x4* o2c = (f32x4*)(out2 + t0g * DIMq);

  struct R { float r0, r2; };
  auto gen = [&](int t, int d, float nzv) -> R {
    int ti = t + (t >> 3);
    float p1 = p1s[ti], nm = nmps[ti];
    float ph = (float)(d + 1) * p1 + inis[d];
    ph -= floorf(ph);
    float s = __builtin_amdgcn_sinf(ph) * 0.1f;
    float noise = fabsf(nm) * nzv;
    R r;
    r.r2 = noise;
    r.r0 = (nm > 0.0f) ? s + noise : noise;
    return r;
  };

#pragma unroll 6
  for (int w = 0; w < Q4; ++w) {
    int q = w * NT + tid;
    int e = q * 4;
    int t = (int)(((unsigned)e * 7282u) >> 16);  // e/9, exact for e<18432
    int d = e - t * 9;
    f32x4 nzv = __builtin_nontemporal_load(&nzc[q]);
    R a = gen(t, d, nzv.x); if (++d == 9) { d = 0; ++t; }
    R bb = gen(t, d, nzv.y); if (++d == 9) { d = 0; ++t; }
    R cc = gen(t, d, nzv.z); if (++d == 9) { d = 0; ++t; }
    R dd = gen(t, d, nzv.w);
    f32x4 r0 = {a.r0, bb.r0, cc.r0, dd.r0};
    f32x4 r2 = {a.r2, bb.r2, cc.r2, dd.r2};
    __builtin_nontemporal_store(r0, &o0c[q]);
    __builtin_nontemporal_store(r2, &o2c[q]);
  }
}

extern "C" void kernel_launch(void* const* d_in, const int* in_sizes, int n_in,
                              void* d_out, int out_size, void* d_ws, size_t ws_size,
                              hipStream_t stream) {
  const float* f0 = (const float*)d_in[0];
  const float* rini = (const float*)d_in[1];
  const float* nz = (const float*)d_in[2];
  float* out = (float*)d_out;
  float* out0 = out;                           // sine_waves (B,L,9)
  float* out1 = out + (size_t)Bq * Lq * DIMq;  // uv (B,L,1)
  float* out2 = out1 + (size_t)Bq * Lq;        // noise (B,L,9)
  double* agg = (double*)d_ws;                 // NBLK doubles = 8 KB
  unsigned* flags = (unsigned*)((char*)d_ws + NBLK * sizeof(double));  // 4 KB

  (void)hipMemsetAsync(flags, 0, NBLK * sizeof(unsigned), stream);
  k_fused<<<NBLK, NT, 0, stream>>>(f0, rini, nz, agg, flags, out0, out1, out2);
}

// Round 7
// 46.016 us; speedup vs baseline: 3.2788x; 1.2629x over previous
//
#include <hip/hip_runtime.h>
#include <math.h>

// SineGenVITS: B=16, L=131072, DIM=9. out = [sine (B,L,9) | uv (B,L,1) | noise (B,L,9)] f32.
//
// phase[b,t,d] = frac( k_d * C_t / SR + rand_ini[b,d] ),  C_t = sum f0[b,0..t] (f64 exact).
// The reference's integer wrap-shifts vanish mod 1; its own f32 error >> ours.
//
// Split structure (R6 post-mortem: fused+lookback spin cost ~10us > launch
// saving). k_partials: per-chunk f64 sums. k_main: block scan + row-prefix
// reduce + streaming generation. CHUNK=1024 -> LDS 9.3KB -> 8 blocks/CU
// (occupancy ~100%, was 44%). NT stores only: keep nz L3-resident across
// replays (R5 FETCH=41MB << 84MB inputs proves L3 absorbs reads).

#define Bq 16
#define Lq 131072
#define DIMq 9
#define CHUNK 1024
#define NCHUNK (Lq / CHUNK)  // 128
#define NBLK (Bq * NCHUNK)   // 2048
#define NT 256
#define PT 4                        // timesteps per thread
#define Q4 (CHUNK * DIMq / 4 / NT)  // 9 float4s per thread in phase 2

typedef float f32x4 __attribute__((ext_vector_type(4)));
typedef double f64x2 __attribute__((ext_vector_type(2)));

__global__ void __launch_bounds__(NT, 8) k_partials(
    const float* __restrict__ f0, double* __restrict__ part) {
  int bc = blockIdx.x;
  int b = bc >> 7, c = bc & 127;
  int tid = threadIdx.x, lane = tid & 63, wave = tid >> 6;
  const f32x4* p = (const f32x4*)(f0 + (size_t)b * Lq + (size_t)c * CHUNK);
  f32x4 x = p[tid];
  double s = ((double)x.x + (double)x.y) + ((double)x.z + (double)x.w);
#pragma unroll
  for (int d = 32; d > 0; d >>= 1) s += __shfl_xor(s, d, 64);
  __shared__ double ws[NT / 64];
  if (lane == 0) ws[wave] = s;
  __syncthreads();
  if (tid == 0) part[bc] = (ws[0] + ws[1]) + (ws[2] + ws[3]);
}

__global__ void __launch_bounds__(NT, 8) k_main(
    const float* __restrict__ f0, const float* __restrict__ rini,
    const float* __restrict__ nz, const double* __restrict__ part,
    float* __restrict__ out0, float* __restrict__ out1,
    float* __restrict__ out2) {
  int bc = blockIdx.x;
  int b = bc >> 7, c = bc & 127;
  int tid = threadIdx.x, lane = tid & 63, wave = tid >> 6;
  size_t t0g = (size_t)b * Lq + (size_t)c * CHUNK;

  __shared__ float p1s[CHUNK + CHUNK / 8];   // frac(C_t/SR), pad-8: idx t+(t>>3)
  __shared__ float nmps[CHUNK + CHUNK / 8];  // +0.003 voiced / -(0.1/3) unvoiced
  __shared__ float inis[DIMq];
  __shared__ double wsum[NT / 64];

  // ---- load f0 chunk, thread-local + wave f64 scan ----
  f32x4 fa = *(const f32x4*)(f0 + t0g + tid * PT);
  float fv[PT] = {fa.x, fa.y, fa.z, fa.w};
  double run = 0.0, inc[PT];
#pragma unroll
  for (int j = 0; j < PT; ++j) { run += (double)fv[j]; inc[j] = run; }
  double tot = run;
#pragma unroll
  for (int d = 1; d < 64; d <<= 1) {
    double o = __shfl_up(tot, d, 64);
    if (lane >= d) tot += o;
  }
  if (lane == 63) wsum[wave] = tot;
  if (tid < DIMq) inis[tid] = rini[b * DIMq + tid];
  __syncthreads();

  // ---- row prefix: reduce the c preceding chunk partials (2 per lane) ----
  f64x2 pp = ((const f64x2*)(part + (b << 7)))[lane];
  double pv = ((2 * lane < c) ? pp.x : 0.0) + ((2 * lane + 1 < c) ? pp.y : 0.0);
#pragma unroll
  for (int d = 32; d > 0; d >>= 1) pv += __shfl_xor(pv, d, 64);
  double wpre = 0.0;
  for (int w = 0; w < wave; ++w) wpre += wsum[w];
  double base = pv + wpre + (tot - run);  // exclusive prefix for this thread

  const double invsr = 1.0 / 22050.0;
  const float nampU = (float)(0.1 / 3.0);
  float uvv[PT];
#pragma unroll
  for (int j = 0; j < PT; ++j) {
    double ph = (base + inc[j]) * invsr;
    ph -= floor(ph);
    int t = tid * PT + j;
    p1s[t + (t >> 3)] = (float)ph;
    bool v = fv[j] > 0.0f;
    nmps[t + (t >> 3)] = v ? 0.003f : -nampU;
    uvv[j] = v ? 1.0f : 0.0f;
  }
  f32x4 u0 = {uvv[0], uvv[1], uvv[2], uvv[3]};
  __builtin_nontemporal_store(u0, (f32x4*)(out1 + t0g + tid * PT));
  __syncthreads();

  // ---- phase 2: flat float4 elementwise over chunk*9 elements ----
  const f32x4* nzc = (const f32x4*)(nz + t0g * DIMq);
  f32x4* o0c = (f32x4*)(out0 + t0g * DIMq);
  f32x4* o2c = (f32x4*)(out2 + t0g * DIMq);

  struct R { float r0, r2; };
  auto gen = [&](int t, int d, float nzv) -> R {
    int ti = t + (t >> 3);
    float p1 = p1s[ti], nm = nmps[ti];
    float ph = (float)(d + 1) * p1 + inis[d];
    ph -= floorf(ph);
    float s = __builtin_amdgcn_sinf(ph) * 0.1f;
    float noise = fabsf(nm) * nzv;
    R r;
    r.r2 = noise;
    r.r0 = (nm > 0.0f) ? s + noise : noise;
    return r;
  };

#pragma unroll 3
  for (int w = 0; w < Q4; ++w) {
    int q = w * NT + tid;
    int e = q * 4;
    int t = (int)(((unsigned)e * 7282u) >> 16);  // e/9, exact for e<18432
    int d = e - t * 9;
    f32x4 nzv = nzc[q];  // plain load: keep nz L2/L3-resident across replays
    R a = gen(t, d, nzv.x); if (++d == 9) { d = 0; ++t; }
    R bb = gen(t, d, nzv.y); if (++d == 9) { d = 0; ++t; }
    R cc = gen(t, d, nzv.z); if (++d == 9) { d = 0; ++t; }
    R dd = gen(t, d, nzv.w);
    f32x4 r0 = {a.r0, bb.r0, cc.r0, dd.r0};
    f32x4 r2 = {a.r2, bb.r2, cc.r2, dd.r2};
    __builtin_nontemporal_store(r0, &o0c[q]);
    __builtin_nontemporal_store(r2, &o2c[q]);
  }
}

extern "C" void kernel_launch(void* const* d_in, const int* in_sizes, int n_in,
                              void* d_out, int out_size, void* d_ws, size_t ws_size,
                              hipStream_t stream) {
  const float* f0 = (const float*)d_in[0];
  const float* rini = (const float*)d_in[1];
  const float* nz = (const float*)d_in[2];
  float* out = (float*)d_out;
  float* out0 = out;                           // sine_waves (B,L,9)
  float* out1 = out + (size_t)Bq * Lq * DIMq;  // uv (B,L,1)
  float* out2 = out1 + (size_t)Bq * Lq;        // noise (B,L,9)
  double* part = (double*)d_ws;                // NBLK doubles = 16 KB

  k_partials<<<NBLK, NT, 0, stream>>>(f0, part);
  k_main<<<NBLK, NT, 0, stream>>>(f0, rini, nz, part, out0, out1, out2);
}